// Round 1
// baseline (1628.989 us; speedup 1.0000x reference)
//
#include <hip/hip_runtime.h>
#include <hip/hip_bf16.h>

#define NN_NODES 100000
#define NE_EDGES 1000000
#define D_IN 512
#define D_H0 512
#define D_H1 256
#define D_C  64

using short8 = __attribute__((ext_vector_type(8))) short;
using f32x4  = __attribute__((ext_vector_type(4))) float;
using u16x4  = __attribute__((ext_vector_type(4))) unsigned short;

static __device__ __forceinline__ unsigned short f2bf(float x){
    return __builtin_bit_cast(unsigned short, __float2bfloat16(x));
}
static __device__ __forceinline__ float bf2f(unsigned short u){
    return __bfloat162float(__builtin_bit_cast(__hip_bfloat16, u));
}

// ---------------- weight split: fp32 -> bf16 hi + bf16 lo ----------------
__global__ void split_fp32_kernel(const float* __restrict__ w,
                                  unsigned short* __restrict__ hi,
                                  unsigned short* __restrict__ lo, int n){
    int i = blockIdx.x * blockDim.x + threadIdx.x;
    if (i < n){
        float x = w[i];
        unsigned short h = f2bf(x);
        hi[i] = h;
        lo[i] = f2bf(x - bf2f(h));
    }
}

// ---------------- GEMM: C[M,NN] = act( A[M,K] * B[NN,K]^T + bias ) ----------------
// B given pre-split as Bhi/Blo bf16 [NN][K].
// SPLIT_A: A is fp32, split into hi/lo during staging (3 MFMAs per pair)
// else:    A is bf16 (exact), 2 MFMAs per pair.
template<bool SPLIT_A, bool RELU, bool OUT_BF16>
__global__ __launch_bounds__(256) void gemm_kernel(
    const void* __restrict__ Araw,
    const unsigned short* __restrict__ Bhi,
    const unsigned short* __restrict__ Blo,
    const float* __restrict__ bias,
    void* __restrict__ Oraw,
    int M, int NNc, int K)
{
    constexpr int BM = 128, BN = 64, BK = 32, LDT = 40; // LDT: LDS row stride (shorts), pads banks
    __shared__ unsigned short sA_hi[BM * LDT];
    __shared__ unsigned short sA_lo[SPLIT_A ? BM * LDT : 8];
    __shared__ unsigned short sB_hi[BN * LDT];
    __shared__ unsigned short sB_lo[BN * LDT];

    const int tid  = threadIdx.x;
    const int lane = tid & 63;
    const int wv   = tid >> 6;
    const int wm   = wv >> 1;   // 0..1 : wave row
    const int wn   = wv & 1;    // 0..1 : wave col
    const int bm0  = blockIdx.x * BM;
    const int bn0  = blockIdx.y * BN;

    const float*          Af = (const float*)Araw;
    const unsigned short* Ab = (const unsigned short*)Araw;

    f32x4 acc[4][2] = {};

    for (int k0 = 0; k0 < K; k0 += BK){
        // ---- stage B tiles (64 x 32 bf16, hi & lo) ----
        {
            int row = tid >> 2;             // 0..63
            int c8  = (tid & 3) * 8;        // 0,8,16,24
            size_t g = (size_t)(bn0 + row) * K + k0 + c8;
            *(short8*)&sB_hi[row * LDT + c8] = *(const short8*)(Bhi + g);
            *(short8*)&sB_lo[row * LDT + c8] = *(const short8*)(Blo + g);
        }
        // ---- stage A tile ----
        if constexpr (SPLIT_A){
            // fp32 A: 128x32 floats; 4 passes of 32 rows; thread: 4 floats
            for (int ps = 0; ps < 4; ps++){
                int row = ps * 32 + (tid >> 3);
                int c4  = (tid & 7) * 4;
                int rg  = bm0 + row;
                float4 v = make_float4(0.f, 0.f, 0.f, 0.f);
                if (rg < M) v = *(const float4*)(Af + (size_t)rg * K + k0 + c4);
                u16x4 hh, ll;
                hh[0]=f2bf(v.x); hh[1]=f2bf(v.y); hh[2]=f2bf(v.z); hh[3]=f2bf(v.w);
                ll[0]=f2bf(v.x-bf2f(hh[0])); ll[1]=f2bf(v.y-bf2f(hh[1]));
                ll[2]=f2bf(v.z-bf2f(hh[2])); ll[3]=f2bf(v.w-bf2f(hh[3]));
                *(u16x4*)&sA_hi[row * LDT + c4] = hh;
                *(u16x4*)&sA_lo[row * LDT + c4] = ll;
            }
        } else {
            // bf16 A: 128x32 shorts; 2 passes of 64 rows; thread: 8 shorts
            for (int ps = 0; ps < 2; ps++){
                int row = ps * 64 + (tid >> 2);
                int c8  = (tid & 3) * 8;
                int rg  = bm0 + row;
                short8 v = {};
                if (rg < M) v = *(const short8*)(Ab + (size_t)rg * K + k0 + c8);
                *(short8*)&sA_hi[row * LDT + c8] = v;
            }
        }
        __syncthreads();

        // ---- compute ----
        short8 bh[2], bl[2];
        #pragma unroll
        for (int nf = 0; nf < 2; nf++){
            int r = wn * 32 + nf * 16 + (lane & 15);
            int c = (lane >> 4) * 8;
            bh[nf] = *(const short8*)&sB_hi[r * LDT + c];
            bl[nf] = *(const short8*)&sB_lo[r * LDT + c];
        }
        #pragma unroll
        for (int mf = 0; mf < 4; mf++){
            int r = wm * 64 + mf * 16 + (lane & 15);
            int c = (lane >> 4) * 8;
            short8 ah = *(const short8*)&sA_hi[r * LDT + c];
            short8 al;
            if constexpr (SPLIT_A) al = *(const short8*)&sA_lo[r * LDT + c];
            #pragma unroll
            for (int nf = 0; nf < 2; nf++){
                acc[mf][nf] = __builtin_amdgcn_mfma_f32_16x16x32_bf16(ah, bh[nf], acc[mf][nf], 0, 0, 0);
                acc[mf][nf] = __builtin_amdgcn_mfma_f32_16x16x32_bf16(ah, bl[nf], acc[mf][nf], 0, 0, 0);
                if constexpr (SPLIT_A)
                    acc[mf][nf] = __builtin_amdgcn_mfma_f32_16x16x32_bf16(al, bh[nf], acc[mf][nf], 0, 0, 0);
            }
        }
        __syncthreads();
    }

    // ---- epilogue: bias (+relu), store ----
    #pragma unroll
    for (int mf = 0; mf < 4; mf++){
        #pragma unroll
        for (int nf = 0; nf < 2; nf++){
            #pragma unroll
            for (int r = 0; r < 4; r++){
                int rg = bm0 + wm * 64 + mf * 16 + (lane >> 4) * 4 + r;
                int cg = bn0 + wn * 32 + nf * 16 + (lane & 15);
                if (rg < M){
                    float v = acc[mf][nf][r] + bias[cg];
                    if constexpr (RELU) v = fmaxf(v, 0.f);
                    if constexpr (OUT_BF16)
                        ((unsigned short*)Oraw)[(size_t)rg * NNc + cg] = f2bf(v);
                    else
                        ((float*)Oraw)[(size_t)rg * NNc + cg] = v;
                }
            }
        }
    }
}

// ---------------- graph preprocessing ----------------
__global__ void degrees_kernel(const int* __restrict__ src, const int* __restrict__ dst,
                               int* __restrict__ dout, int* __restrict__ din){
    int e = blockIdx.x * blockDim.x + threadIdx.x;
    if (e < NE_EDGES){
        atomicAdd(&dout[src[e]], 1);
        atomicAdd(&din[dst[e]], 1);
    }
}

__global__ void norm_kernel(const int* __restrict__ dout, const int* __restrict__ din,
                            float* __restrict__ ns, float* __restrict__ nd, int n){
    int i = blockIdx.x * blockDim.x + threadIdx.x;
    if (i < n){
        ns[i] = rsqrtf((float)(dout[i] > 1 ? dout[i] : 1));
        nd[i] = rsqrtf((float)(din[i]  > 1 ? din[i]  : 1));
    }
}

__global__ __launch_bounds__(256) void scan1_kernel(const int* __restrict__ din,
                                                    int* __restrict__ part,
                                                    int* __restrict__ bsum, int n){
    __shared__ int s[256];
    int i = blockIdx.x * 256 + threadIdx.x;
    int v = (i < n) ? din[i] : 0;
    s[threadIdx.x] = v;
    __syncthreads();
    for (int off = 1; off < 256; off <<= 1){
        int t = (threadIdx.x >= off) ? s[threadIdx.x - off] : 0;
        __syncthreads();
        s[threadIdx.x] += t;
        __syncthreads();
    }
    if (i < n) part[i] = s[threadIdx.x];            // inclusive scan within block
    if (threadIdx.x == 255) bsum[blockIdx.x] = s[255];
}

__global__ __launch_bounds__(512) void scan2_kernel(int* __restrict__ bsum, int nb){
    __shared__ int s[512];
    int v = (threadIdx.x < nb) ? bsum[threadIdx.x] : 0;
    s[threadIdx.x] = v;
    __syncthreads();
    for (int off = 1; off < 512; off <<= 1){
        int t = (threadIdx.x >= off) ? s[threadIdx.x - off] : 0;
        __syncthreads();
        s[threadIdx.x] += t;
        __syncthreads();
    }
    if (threadIdx.x < nb) bsum[threadIdx.x] = s[threadIdx.x]; // inclusive
}

__global__ void scan3_kernel(const int* __restrict__ part, const int* __restrict__ din,
                             const int* __restrict__ bsum, int* __restrict__ offs,
                             int* __restrict__ cur, int n){
    int i = blockIdx.x * 256 + threadIdx.x;
    if (i < n){
        int base = (blockIdx.x > 0) ? bsum[blockIdx.x - 1] : 0;
        int excl = base + part[i] - din[i];
        offs[i] = excl;
        cur[i]  = excl;
    }
}

__global__ void fill_kernel(const int* __restrict__ src, const int* __restrict__ dst,
                            int* __restrict__ cur, int* __restrict__ csr){
    int e = blockIdx.x * blockDim.x + threadIdx.x;
    if (e < NE_EDGES){
        int d = dst[e];
        int pos = atomicAdd(&cur[d], 1);
        csr[pos] = src[e];
    }
}

// ---------------- APPNP propagation: one wave per dst node ----------------
__global__ __launch_bounds__(256) void propagate_kernel(
    const float* __restrict__ hin, const float* __restrict__ h0,
    float* __restrict__ hout,
    const int* __restrict__ offs, const int* __restrict__ din,
    const int* __restrict__ csr,
    const float* __restrict__ ns, const float* __restrict__ nd)
{
    int wv   = threadIdx.x >> 6;
    int lane = threadIdx.x & 63;
    int node = blockIdx.x * 4 + wv;
    if (node >= NN_NODES) return;
    int start = offs[node];
    int deg   = din[node];
    float acc = 0.f;
    for (int j = 0; j < deg; j++){
        int s = csr[start + j];
        s = __builtin_amdgcn_readfirstlane(s);
        float w = ns[s];
        acc += hin[(size_t)s * D_C + lane] * w;
    }
    float out = 0.9f * acc * nd[node] + 0.1f * h0[(size_t)node * D_C + lane];
    hout[(size_t)node * D_C + lane] = out;
}

// ---------------- launch ----------------
extern "C" void kernel_launch(void* const* d_in, const int* in_sizes, int n_in,
                              void* d_out, int out_size, void* d_ws, size_t ws_size,
                              hipStream_t stream)
{
    const float* features = (const float*)d_in[0];
    const int*   edge     = (const int*)d_in[1];
    const float* W0 = (const float*)d_in[2];
    const float* b0 = (const float*)d_in[3];
    const float* W1 = (const float*)d_in[4];
    const float* b1 = (const float*)d_in[5];
    const float* W2 = (const float*)d_in[6];
    const float* b2 = (const float*)d_in[7];
    const int* src = edge;
    const int* dst = edge + NE_EDGES;

    char* p = (char*)d_ws;
    auto alloc = [&](size_t bytes) -> char* {
        char* r = p;
        p += (bytes + 255) & ~(size_t)255;
        return r;
    };

    unsigned short* w0hi = (unsigned short*)alloc((size_t)D_H0 * D_IN * 2);
    unsigned short* w0lo = (unsigned short*)alloc((size_t)D_H0 * D_IN * 2);
    unsigned short* w1hi = (unsigned short*)alloc((size_t)D_H1 * D_H0 * 2);
    unsigned short* w1lo = (unsigned short*)alloc((size_t)D_H1 * D_H0 * 2);
    unsigned short* w2hi = (unsigned short*)alloc((size_t)D_C * D_H1 * 2);
    unsigned short* w2lo = (unsigned short*)alloc((size_t)D_C * D_H1 * 2);
    unsigned short* act1 = (unsigned short*)alloc((size_t)NN_NODES * D_H0 * 2);
    unsigned short* act2 = (unsigned short*)alloc((size_t)NN_NODES * D_H1 * 2);
    float* h0   = (float*)alloc((size_t)NN_NODES * D_C * 4);
    float* hA   = (float*)alloc((size_t)NN_NODES * D_C * 4);
    float* hB   = (float*)alloc((size_t)NN_NODES * D_C * 4);
    int* deg_out = (int*)alloc((size_t)NN_NODES * 4);
    int* deg_in  = (int*)alloc((size_t)NN_NODES * 4);
    float* nsrc  = (float*)alloc((size_t)NN_NODES * 4);
    float* ndst  = (float*)alloc((size_t)NN_NODES * 4);
    int* part    = (int*)alloc((size_t)NN_NODES * 4);
    int* bsum    = (int*)alloc(2048);
    int* offs    = (int*)alloc((size_t)NN_NODES * 4);
    int* cur     = (int*)alloc((size_t)NN_NODES * 4);
    int* csr     = (int*)alloc((size_t)NE_EDGES * 4);
    if ((size_t)(p - (char*)d_ws) > ws_size) return;  // workspace too small: fail visibly

    // --- graph preprocessing ---
    hipMemsetAsync(deg_out, 0, (size_t)NN_NODES * 4, stream);
    hipMemsetAsync(deg_in,  0, (size_t)NN_NODES * 4, stream);
    degrees_kernel<<<(NE_EDGES + 255) / 256, 256, 0, stream>>>(src, dst, deg_out, deg_in);
    norm_kernel<<<(NN_NODES + 255) / 256, 256, 0, stream>>>(deg_out, deg_in, nsrc, ndst, NN_NODES);
    int nb = (NN_NODES + 255) / 256;
    scan1_kernel<<<nb, 256, 0, stream>>>(deg_in, part, bsum, NN_NODES);
    scan2_kernel<<<1, 512, 0, stream>>>(bsum, nb);
    scan3_kernel<<<nb, 256, 0, stream>>>(part, deg_in, bsum, offs, cur, NN_NODES);
    fill_kernel<<<(NE_EDGES + 255) / 256, 256, 0, stream>>>(src, dst, cur, csr);

    // --- split weights ---
    split_fp32_kernel<<<(D_H0 * D_IN + 255) / 256, 256, 0, stream>>>(W0, w0hi, w0lo, D_H0 * D_IN);
    split_fp32_kernel<<<(D_H1 * D_H0 + 255) / 256, 256, 0, stream>>>(W1, w1hi, w1lo, D_H1 * D_H0);
    split_fp32_kernel<<<(D_C * D_H1 + 255) / 256, 256, 0, stream>>>(W2, w2hi, w2lo, D_C * D_H1);

    // --- MLP ---
    int mtiles = (NN_NODES + 127) / 128;
    gemm_kernel<true, true, true><<<dim3(mtiles, D_H0 / 64), 256, 0, stream>>>(
        features, w0hi, w0lo, b0, act1, NN_NODES, D_H0, D_IN);
    gemm_kernel<false, true, true><<<dim3(mtiles, D_H1 / 64), 256, 0, stream>>>(
        act1, w1hi, w1lo, b1, act2, NN_NODES, D_H1, D_H0);
    gemm_kernel<false, false, false><<<dim3(mtiles, D_C / 64), 256, 0, stream>>>(
        act2, w2hi, w2lo, b2, h0, NN_NODES, D_C, D_H1);

    // --- APPNP: 10 propagation steps ---
    const float* curh = h0;
    float* bufs[2] = { hA, hB };
    int pb = (NN_NODES + 3) / 4;
    for (int it = 0; it < 10; it++){
        float* out = (it == 9) ? (float*)d_out : bufs[it & 1];
        propagate_kernel<<<pb, 256, 0, stream>>>(curh, h0, out, offs, deg_in, csr, nsrc, ndst);
        curh = out;
    }
}

// Round 2
// 1246.830 us; speedup vs baseline: 1.3065x; 1.3065x over previous
//
#include <hip/hip_runtime.h>
#include <hip/hip_bf16.h>

#define NN_NODES 100000
#define NE_EDGES 1000000
#define D_IN 512
#define D_H0 512
#define D_H1 256
#define D_C  64

using short8 = __attribute__((ext_vector_type(8))) short;
using f32x4  = __attribute__((ext_vector_type(4))) float;
using u16x4  = __attribute__((ext_vector_type(4))) unsigned short;

static __device__ __forceinline__ unsigned short f2bf(float x){
    return __builtin_bit_cast(unsigned short, __float2bfloat16(x));
}
static __device__ __forceinline__ float bf2f(unsigned short u){
    return __bfloat162float(__builtin_bit_cast(__hip_bfloat16, u));
}

// ---------------- weight split: fp32 -> bf16 hi + bf16 lo ----------------
__global__ void split_fp32_kernel(const float* __restrict__ w,
                                  unsigned short* __restrict__ hi,
                                  unsigned short* __restrict__ lo, int n){
    int i = blockIdx.x * blockDim.x + threadIdx.x;
    if (i < n){
        float x = w[i];
        unsigned short h = f2bf(x);
        hi[i] = h;
        lo[i] = f2bf(x - bf2f(h));
    }
}

// ---------------- GEMM: C[M,NN] = act( A[M,K] * B[NN,K]^T + bias ) ----------------
// B pre-split as Bhi/Blo bf16 [NN][K].
// SPLIT_A: A fp32, split during staging (3 MFMAs/pair); else A bf16 (2 MFMAs/pair).
// OMODE: 0 = fp32 out, 1 = bf16 out, 2 = dual fp32 out (O1 = v, O2 = v*scale[row])
// Grid: (NNc/BN_T, mtiles) -- blockIdx.x = bn varies fastest so consecutive
// blocks share the same A rows (L2/L3 reuse); B is small and L2-resident.
template<bool SPLIT_A, bool RELU, int OMODE, int BN_T>
__global__ __launch_bounds__(256) void gemm_kernel(
    const void* __restrict__ Araw,
    const unsigned short* __restrict__ Bhi,
    const unsigned short* __restrict__ Blo,
    const float* __restrict__ bias,
    void* __restrict__ O1,
    float* __restrict__ O2,
    const float* __restrict__ scale,
    int M, int NNc, int K)
{
    constexpr int BM = 128, BK = 32, LDT = 40;   // LDT pads rows to 20 banks -> 2-way max
    constexpr int NF = BN_T / 32;                // n-fragments per wave (wave tile 64 x BN_T/2)
    __shared__ unsigned short sA_hi[BM * LDT];
    __shared__ unsigned short sA_lo[SPLIT_A ? BM * LDT : 8];
    __shared__ unsigned short sB_hi[BN_T * LDT];
    __shared__ unsigned short sB_lo[BN_T * LDT];

    const int tid  = threadIdx.x;
    const int lane = tid & 63;
    const int wv   = tid >> 6;
    const int wm   = wv >> 1;   // 0..1
    const int wn   = wv & 1;    // 0..1
    const int bm0  = blockIdx.y * BM;
    const int bn0  = blockIdx.x * BN_T;

    const float*          Af = (const float*)Araw;
    const unsigned short* Ab = (const unsigned short*)Araw;

    f32x4 acc[4][NF] = {};

    for (int k0 = 0; k0 < K; k0 += BK){
        // ---- stage B tiles (BN_T x 32 bf16, hi & lo) ----
        for (int i = tid; i < BN_T * 4; i += 256){
            int row = i >> 2;
            int c8  = (i & 3) * 8;
            size_t g = (size_t)(bn0 + row) * K + k0 + c8;
            *(short8*)&sB_hi[row * LDT + c8] = *(const short8*)(Bhi + g);
            *(short8*)&sB_lo[row * LDT + c8] = *(const short8*)(Blo + g);
        }
        // ---- stage A tile ----
        if constexpr (SPLIT_A){
            for (int i = tid; i < BM * 8; i += 256){
                int row = i >> 3;
                int c4  = (i & 7) * 4;
                int rg  = bm0 + row;
                float4 v = make_float4(0.f, 0.f, 0.f, 0.f);
                if (rg < M) v = *(const float4*)(Af + (size_t)rg * K + k0 + c4);
                u16x4 hh, ll;
                hh[0]=f2bf(v.x); hh[1]=f2bf(v.y); hh[2]=f2bf(v.z); hh[3]=f2bf(v.w);
                ll[0]=f2bf(v.x-bf2f(hh[0])); ll[1]=f2bf(v.y-bf2f(hh[1]));
                ll[2]=f2bf(v.z-bf2f(hh[2])); ll[3]=f2bf(v.w-bf2f(hh[3]));
                *(u16x4*)&sA_hi[row * LDT + c4] = hh;
                *(u16x4*)&sA_lo[row * LDT + c4] = ll;
            }
        } else {
            for (int i = tid; i < BM * 4; i += 256){
                int row = i >> 2;
                int c8  = (i & 3) * 8;
                int rg  = bm0 + row;
                short8 v = {};
                if (rg < M) v = *(const short8*)(Ab + (size_t)rg * K + k0 + c8);
                *(short8*)&sA_hi[row * LDT + c8] = v;
            }
        }
        __syncthreads();

        // ---- compute ----
        short8 bh[NF], bl[NF];
        #pragma unroll
        for (int nf = 0; nf < NF; nf++){
            int r = wn * (BN_T / 2) + nf * 16 + (lane & 15);
            int c = (lane >> 4) * 8;
            bh[nf] = *(const short8*)&sB_hi[r * LDT + c];
            bl[nf] = *(const short8*)&sB_lo[r * LDT + c];
        }
        #pragma unroll
        for (int mf = 0; mf < 4; mf++){
            int r = wm * 64 + mf * 16 + (lane & 15);
            int c = (lane >> 4) * 8;
            short8 ah = *(const short8*)&sA_hi[r * LDT + c];
            short8 al;
            if constexpr (SPLIT_A) al = *(const short8*)&sA_lo[r * LDT + c];
            #pragma unroll
            for (int nf = 0; nf < NF; nf++){
                acc[mf][nf] = __builtin_amdgcn_mfma_f32_16x16x32_bf16(ah, bh[nf], acc[mf][nf], 0, 0, 0);
                acc[mf][nf] = __builtin_amdgcn_mfma_f32_16x16x32_bf16(ah, bl[nf], acc[mf][nf], 0, 0, 0);
                if constexpr (SPLIT_A)
                    acc[mf][nf] = __builtin_amdgcn_mfma_f32_16x16x32_bf16(al, bh[nf], acc[mf][nf], 0, 0, 0);
            }
        }
        __syncthreads();
    }

    // ---- epilogue ----
    #pragma unroll
    for (int mf = 0; mf < 4; mf++){
        #pragma unroll
        for (int nf = 0; nf < NF; nf++){
            #pragma unroll
            for (int r = 0; r < 4; r++){
                int rg = bm0 + wm * 64 + mf * 16 + (lane >> 4) * 4 + r;
                int cg = bn0 + wn * (BN_T / 2) + nf * 16 + (lane & 15);
                if (rg < M){
                    float v = acc[mf][nf][r] + bias[cg];
                    if constexpr (RELU) v = fmaxf(v, 0.f);
                    if constexpr (OMODE == 1)
                        ((unsigned short*)O1)[(size_t)rg * NNc + cg] = f2bf(v);
                    else if constexpr (OMODE == 0)
                        ((float*)O1)[(size_t)rg * NNc + cg] = v;
                    else {
                        ((float*)O1)[(size_t)rg * NNc + cg] = v;
                        O2[(size_t)rg * NNc + cg] = v * scale[rg];
                    }
                }
            }
        }
    }
}

// ---------------- graph preprocessing ----------------
__global__ void degrees_kernel(const int* __restrict__ src, const int* __restrict__ dst,
                               int* __restrict__ dout, int* __restrict__ din){
    int e = blockIdx.x * blockDim.x + threadIdx.x;
    if (e < NE_EDGES){
        atomicAdd(&dout[src[e]], 1);
        atomicAdd(&din[dst[e]], 1);
    }
}

__global__ void norm_kernel(const int* __restrict__ dout, const int* __restrict__ din,
                            float* __restrict__ ns, float* __restrict__ nd, int n){
    int i = blockIdx.x * blockDim.x + threadIdx.x;
    if (i < n){
        ns[i] = rsqrtf((float)(dout[i] > 1 ? dout[i] : 1));
        nd[i] = rsqrtf((float)(din[i]  > 1 ? din[i]  : 1));
    }
}

__global__ __launch_bounds__(256) void scan1_kernel(const int* __restrict__ din,
                                                    int* __restrict__ part,
                                                    int* __restrict__ bsum, int n){
    __shared__ int s[256];
    int i = blockIdx.x * 256 + threadIdx.x;
    int v = (i < n) ? din[i] : 0;
    s[threadIdx.x] = v;
    __syncthreads();
    for (int off = 1; off < 256; off <<= 1){
        int t = (threadIdx.x >= off) ? s[threadIdx.x - off] : 0;
        __syncthreads();
        s[threadIdx.x] += t;
        __syncthreads();
    }
    if (i < n) part[i] = s[threadIdx.x];
    if (threadIdx.x == 255) bsum[blockIdx.x] = s[255];
}

__global__ __launch_bounds__(512) void scan2_kernel(int* __restrict__ bsum, int nb){
    __shared__ int s[512];
    int v = (threadIdx.x < nb) ? bsum[threadIdx.x] : 0;
    s[threadIdx.x] = v;
    __syncthreads();
    for (int off = 1; off < 512; off <<= 1){
        int t = (threadIdx.x >= off) ? s[threadIdx.x - off] : 0;
        __syncthreads();
        s[threadIdx.x] += t;
        __syncthreads();
    }
    if (threadIdx.x < nb) bsum[threadIdx.x] = s[threadIdx.x];
}

__global__ void scan3_kernel(const int* __restrict__ part, const int* __restrict__ din,
                             const int* __restrict__ bsum, int* __restrict__ offs,
                             int* __restrict__ cur, int n){
    int i = blockIdx.x * 256 + threadIdx.x;
    if (i < n){
        int base = (blockIdx.x > 0) ? bsum[blockIdx.x - 1] : 0;
        int excl = base + part[i] - din[i];
        offs[i] = excl;
        cur[i]  = excl;
    }
}

__global__ void fill_kernel(const int* __restrict__ src, const int* __restrict__ dst,
                            int* __restrict__ cur, int* __restrict__ csr){
    int e = blockIdx.x * blockDim.x + threadIdx.x;
    if (e < NE_EDGES){
        int d = dst[e];
        int pos = atomicAdd(&cur[d], 1);
        csr[pos] = src[e];
    }
}

// ---------------- APPNP propagation ----------------
// hs = h * norm_src (pre-scaled by producer). One wave per node; 4 groups of
// 16 lanes process 4 edges concurrently, each group reads the 64-float row as
// float4/lane. Cross-group shfl_xor reduce at the end.
// Writes hout and (unless last iter) houts = hout * norm_src for next gather.
__global__ __launch_bounds__(256) void propagate_kernel(
    const float* __restrict__ hs, const float* __restrict__ h0,
    float* __restrict__ hout, float* __restrict__ houts,
    const int* __restrict__ offs, const int* __restrict__ din,
    const int* __restrict__ csr,
    const float* __restrict__ ns, const float* __restrict__ nd)
{
    int wv   = threadIdx.x >> 6;
    int lane = threadIdx.x & 63;
    int grp  = lane >> 4;        // 0..3
    int gl   = lane & 15;        // lane within group
    int node = blockIdx.x * 4 + wv;
    if (node >= NN_NODES) return;
    int start = offs[node];
    int deg   = din[node];
    f32x4 acc = {};
    for (int j = grp; j < deg; j += 4){
        int s = csr[start + j];
        const f32x4 v = *(const f32x4*)(hs + (size_t)s * D_C + gl * 4);
        acc[0] += v[0]; acc[1] += v[1]; acc[2] += v[2]; acc[3] += v[3];
    }
    #pragma unroll
    for (int i = 0; i < 4; i++){
        acc[i] += __shfl_xor(acc[i], 16, 64);
        acc[i] += __shfl_xor(acc[i], 32, 64);
    }
    if (grp == 0){
        float ndv = nd[node];
        f32x4 h0v = *(const f32x4*)(h0 + (size_t)node * D_C + gl * 4);
        f32x4 out;
        #pragma unroll
        for (int i = 0; i < 4; i++) out[i] = 0.9f * acc[i] * ndv + 0.1f * h0v[i];
        *(f32x4*)(hout + (size_t)node * D_C + gl * 4) = out;
        if (houts){
            float nsv = ns[node];
            f32x4 o2;
            #pragma unroll
            for (int i = 0; i < 4; i++) o2[i] = out[i] * nsv;
            *(f32x4*)(houts + (size_t)node * D_C + gl * 4) = o2;
        }
    }
}

// ---------------- launch ----------------
extern "C" void kernel_launch(void* const* d_in, const int* in_sizes, int n_in,
                              void* d_out, int out_size, void* d_ws, size_t ws_size,
                              hipStream_t stream)
{
    const float* features = (const float*)d_in[0];
    const int*   edge     = (const int*)d_in[1];
    const float* W0 = (const float*)d_in[2];
    const float* b0 = (const float*)d_in[3];
    const float* W1 = (const float*)d_in[4];
    const float* b1 = (const float*)d_in[5];
    const float* W2 = (const float*)d_in[6];
    const float* b2 = (const float*)d_in[7];
    const int* src = edge;
    const int* dst = edge + NE_EDGES;

    char* p = (char*)d_ws;
    auto alloc = [&](size_t bytes) -> char* {
        char* r = p;
        p += (bytes + 255) & ~(size_t)255;
        return r;
    };

    unsigned short* w0hi = (unsigned short*)alloc((size_t)D_H0 * D_IN * 2);
    unsigned short* w0lo = (unsigned short*)alloc((size_t)D_H0 * D_IN * 2);
    unsigned short* w1hi = (unsigned short*)alloc((size_t)D_H1 * D_H0 * 2);
    unsigned short* w1lo = (unsigned short*)alloc((size_t)D_H1 * D_H0 * 2);
    unsigned short* w2hi = (unsigned short*)alloc((size_t)D_C * D_H1 * 2);
    unsigned short* w2lo = (unsigned short*)alloc((size_t)D_C * D_H1 * 2);
    unsigned short* act1 = (unsigned short*)alloc((size_t)NN_NODES * D_H0 * 2);
    unsigned short* act2 = (unsigned short*)alloc((size_t)NN_NODES * D_H1 * 2);
    float* h0   = (float*)alloc((size_t)NN_NODES * D_C * 4);
    float* hA   = (float*)alloc((size_t)NN_NODES * D_C * 4);
    float* hB   = (float*)alloc((size_t)NN_NODES * D_C * 4);
    int* deg_out = (int*)alloc((size_t)NN_NODES * 4);
    int* deg_in  = (int*)alloc((size_t)NN_NODES * 4);
    float* nsrc  = (float*)alloc((size_t)NN_NODES * 4);
    float* ndst  = (float*)alloc((size_t)NN_NODES * 4);
    int* part    = (int*)alloc((size_t)NN_NODES * 4);
    int* bsum    = (int*)alloc(2048);
    int* offs    = (int*)alloc((size_t)NN_NODES * 4);
    int* cur     = (int*)alloc((size_t)NN_NODES * 4);
    int* csr     = (int*)alloc((size_t)NE_EDGES * 4);
    if ((size_t)(p - (char*)d_ws) > ws_size) return;

    // scaled h buffers alias act1 (act1 is dead after GEMM2, these are written
    // only by GEMM3 / propagate which run later on the same stream)
    float* h0s = (float*)act1;
    float* hAs = h0s + (size_t)NN_NODES * D_C;
    float* hBs = hAs + (size_t)NN_NODES * D_C;

    // --- graph preprocessing ---
    hipMemsetAsync(deg_out, 0, (size_t)NN_NODES * 4, stream);
    hipMemsetAsync(deg_in,  0, (size_t)NN_NODES * 4, stream);
    degrees_kernel<<<(NE_EDGES + 255) / 256, 256, 0, stream>>>(src, dst, deg_out, deg_in);
    norm_kernel<<<(NN_NODES + 255) / 256, 256, 0, stream>>>(deg_out, deg_in, nsrc, ndst, NN_NODES);
    int nb = (NN_NODES + 255) / 256;
    scan1_kernel<<<nb, 256, 0, stream>>>(deg_in, part, bsum, NN_NODES);
    scan2_kernel<<<1, 512, 0, stream>>>(bsum, nb);
    scan3_kernel<<<nb, 256, 0, stream>>>(part, deg_in, bsum, offs, cur, NN_NODES);
    fill_kernel<<<(NE_EDGES + 255) / 256, 256, 0, stream>>>(src, dst, cur, csr);

    // --- split weights ---
    split_fp32_kernel<<<(D_H0 * D_IN + 255) / 256, 256, 0, stream>>>(W0, w0hi, w0lo, D_H0 * D_IN);
    split_fp32_kernel<<<(D_H1 * D_H0 + 255) / 256, 256, 0, stream>>>(W1, w1hi, w1lo, D_H1 * D_H0);
    split_fp32_kernel<<<(D_C * D_H1 + 255) / 256, 256, 0, stream>>>(W2, w2hi, w2lo, D_C * D_H1);

    // --- MLP (bn on blockIdx.x: consecutive blocks share A rows) ---
    int mtiles = (NN_NODES + 127) / 128;
    gemm_kernel<true, true, 1, 128><<<dim3(D_H0 / 128, mtiles), 256, 0, stream>>>(
        features, w0hi, w0lo, b0, act1, nullptr, nullptr, NN_NODES, D_H0, D_IN);
    gemm_kernel<false, true, 1, 128><<<dim3(D_H1 / 128, mtiles), 256, 0, stream>>>(
        act1, w1hi, w1lo, b1, act2, nullptr, nullptr, NN_NODES, D_H1, D_H0);
    gemm_kernel<false, false, 2, 64><<<dim3(1, mtiles), 256, 0, stream>>>(
        act2, w2hi, w2lo, b2, h0, h0s, nsrc, NN_NODES, D_C, D_H1);

    // --- APPNP: 10 propagation steps ---
    const float* curs = h0s;
    float* bufs[2]  = { hA, hB };
    float* bufss[2] = { hAs, hBs };
    int pb = (NN_NODES + 3) / 4;
    for (int it = 0; it < 10; it++){
        float* out  = (it == 9) ? (float*)d_out : bufs[it & 1];
        float* outs = (it == 9) ? nullptr       : bufss[it & 1];
        propagate_kernel<<<pb, 256, 0, stream>>>(curs, h0, out, outs, offs, deg_in, csr, nsrc, ndst);
        curs = outs;
    }
}

// Round 3
// 1081.693 us; speedup vs baseline: 1.5060x; 1.1527x over previous
//
#include <hip/hip_runtime.h>
#include <hip/hip_bf16.h>

#define NN_NODES 100000
#define NE_EDGES 1000000
#define D_IN 512
#define D_H0 512
#define D_H1 256
#define D_C  64

using short8 = __attribute__((ext_vector_type(8))) short;
using f32x4  = __attribute__((ext_vector_type(4))) float;

static __device__ __forceinline__ unsigned short f2bf(float x){
    return __builtin_bit_cast(unsigned short, __float2bfloat16(x));
}
static __device__ __forceinline__ float bf2f(unsigned short u){
    return __bfloat162float(__builtin_bit_cast(__hip_bfloat16, u));
}

// async global->LDS, 16B per lane; LDS dest = wave-uniform base + lane*16
static __device__ __forceinline__ void gll16(const unsigned short* g, unsigned short* l){
    __builtin_amdgcn_global_load_lds(
        (const __attribute__((address_space(1))) unsigned int*)g,
        (__attribute__((address_space(3))) unsigned int*)l, 16, 0, 0);
}

// ---------------- split fp32 -> bf16 hi + bf16 lo, 8 elems/thread ----------------
__global__ __launch_bounds__(256) void split8_kernel(
    const float* __restrict__ w, unsigned short* __restrict__ hi,
    unsigned short* __restrict__ lo, int n8)
{
    int i = blockIdx.x * 256 + threadIdx.x;
    if (i >= n8) return;
    const f32x4 a = *(const f32x4*)(w + (size_t)i * 8);
    const f32x4 b = *(const f32x4*)(w + (size_t)i * 8 + 4);
    short8 h, l;
    #pragma unroll
    for (int j = 0; j < 4; j++){
        unsigned short h1 = f2bf(a[j]);
        h[j] = (short)h1;  l[j] = (short)f2bf(a[j] - bf2f(h1));
        unsigned short h2 = f2bf(b[j]);
        h[j+4] = (short)h2; l[j+4] = (short)f2bf(b[j] - bf2f(h2));
    }
    *(short8*)(hi + (size_t)i * 8) = h;
    *(short8*)(lo + (size_t)i * 8) = l;
}

// ---------------- GEMM: C[M,NNc] = act( A[M,K] * B[NNc,K]^T + bias ) ----------------
// All operands bf16, pre-split. A as Ahi(+Alo if SPLIT_A); B as Bhi/Blo.
// 3 MFMA/pair if SPLIT_A (ah*bh + ah*bl + al*bh) else 2 (a*bh + a*bl).
// OMODE: 0 fp32 out, 1 bf16 out, 2 dual fp32 (O1=v, O2=v*scale[row]).
// BM=128, BK=32 fixed; BN_T in {64,128}. 1-D grid with bijective XCD-chunked
// swizzle: all NBN bn-blocks of an m-tile + consecutive m-tiles share an XCD.
template<bool SPLIT_A, bool RELU, int OMODE, int BN_T, int NBN>
__global__ __launch_bounds__(256) void gemm_kernel(
    const unsigned short* __restrict__ Ahi,
    const unsigned short* __restrict__ Alo,
    const unsigned short* __restrict__ Bhi,
    const unsigned short* __restrict__ Blo,
    const float* __restrict__ bias,
    void* __restrict__ O1, float* __restrict__ O2, const float* __restrict__ scale,
    int M, int NNc, int K, int xq, int xr)
{
    constexpr int BM = 128, BK = 32;
    constexpr int NF = BN_T / 32;           // n-fragments per wave
    constexpr int BBLK = BN_T / 16;         // 16-row load blocks per B tile
    constexpr int ABLK = SPLIT_A ? 16 : 8;
    constexpr int TOT  = ABLK + 2 * BBLK;   // global_load_lds ops per k-step
    constexpr int TPW  = TOT / 4;

    __shared__ unsigned short sA_hi[BM * BK];
    __shared__ unsigned short sA_lo[SPLIT_A ? BM * BK : 8];
    __shared__ unsigned short sB_hi[BN_T * BK];
    __shared__ unsigned short sB_lo[BN_T * BK];

    const int tid  = threadIdx.x;
    const int lane = tid & 63;
    const int wv   = tid >> 6;
    const int wm   = wv >> 1;
    const int wn   = wv & 1;

    // bijective XCD-chunk swizzle (m204): xcd = bid%8 owns a contiguous L-range
    const int bid = blockIdx.x;
    const int xcd = bid & 7;
    const int i8  = bid >> 3;
    const int L   = ((xcd < xr) ? xcd * (xq + 1) : xr * (xq + 1) + (xcd - xr) * xq) + i8;
    const int mt  = L / NBN;
    const int bn  = L - mt * NBN;
    const int bm0 = mt * BM;
    const int bn0 = bn * BN_T;

    const int lrow = lane >> 2;     // row within a 16-row load block
    const int lch  = lane & 3;      // 16B chunk within 64B row

    f32x4 acc[4][NF] = {};

    for (int k0 = 0; k0 < K; k0 += BK){
        // ---- stage all tiles via global_load_lds (no VALU, linear LDS) ----
        #pragma unroll
        for (int t = 0; t < TPW; t++){
            int idx = t * 4 + wv;
            const unsigned short* g; unsigned short* lb; int rb; int isA;
            if constexpr (SPLIT_A){
                if (idx < 8)            { g = Ahi; lb = sA_hi; rb = idx;            isA = 1; }
                else if (idx < 16)      { g = Alo; lb = sA_lo; rb = idx - 8;        isA = 1; }
                else if (idx < 16+BBLK) { g = Bhi; lb = sB_hi; rb = idx - 16;       isA = 0; }
                else                    { g = Blo; lb = sB_lo; rb = idx - 16 - BBLK; isA = 0; }
            } else {
                if (idx < 8)            { g = Ahi; lb = sA_hi; rb = idx;            isA = 1; }
                else if (idx < 8+BBLK)  { g = Bhi; lb = sB_hi; rb = idx - 8;        isA = 0; }
                else                    { g = Blo; lb = sB_lo; rb = idx - 8 - BBLK;  isA = 0; }
            }
            int rl = rb * 16 + lrow;
            int row;
            if (isA){ row = bm0 + rl; if (row > M - 1) row = M - 1; }
            else    { row = bn0 + rl; }
            gll16(g + (size_t)row * K + k0 + lch * 8, lb + rb * 512);
        }
        __syncthreads();   // drains vmcnt -> LDS tiles complete

        // ---- compute ----
        const int fr = lane & 15;
        const int fc = lane >> 4;
        short8 bh[NF], bl[NF];
        #pragma unroll
        for (int nf = 0; nf < NF; nf++){
            int r = wn * (BN_T / 2) + nf * 16 + fr;
            bh[nf] = *(const short8*)&sB_hi[r * 32 + fc * 8];
            bl[nf] = *(const short8*)&sB_lo[r * 32 + fc * 8];
        }
        #pragma unroll
        for (int mf = 0; mf < 4; mf++){
            int r = wm * 64 + mf * 16 + fr;
            short8 ah = *(const short8*)&sA_hi[r * 32 + fc * 8];
            short8 al;
            if constexpr (SPLIT_A) al = *(const short8*)&sA_lo[r * 32 + fc * 8];
            #pragma unroll
            for (int nf = 0; nf < NF; nf++){
                acc[mf][nf] = __builtin_amdgcn_mfma_f32_16x16x32_bf16(ah, bh[nf], acc[mf][nf], 0, 0, 0);
                acc[mf][nf] = __builtin_amdgcn_mfma_f32_16x16x32_bf16(ah, bl[nf], acc[mf][nf], 0, 0, 0);
                if constexpr (SPLIT_A)
                    acc[mf][nf] = __builtin_amdgcn_mfma_f32_16x16x32_bf16(al, bh[nf], acc[mf][nf], 0, 0, 0);
            }
        }
        __syncthreads();
    }

    // ---- epilogue ----
    #pragma unroll
    for (int mf = 0; mf < 4; mf++){
        #pragma unroll
        for (int nf = 0; nf < NF; nf++){
            #pragma unroll
            for (int r = 0; r < 4; r++){
                int rg = bm0 + wm * 64 + mf * 16 + (lane >> 4) * 4 + r;
                int cg = bn0 + wn * (BN_T / 2) + nf * 16 + (lane & 15);
                if (rg < M){
                    float v = acc[mf][nf][r] + bias[cg];
                    if constexpr (RELU) v = fmaxf(v, 0.f);
                    if constexpr (OMODE == 1)
                        ((unsigned short*)O1)[(size_t)rg * NNc + cg] = f2bf(v);
                    else if constexpr (OMODE == 0)
                        ((float*)O1)[(size_t)rg * NNc + cg] = v;
                    else {
                        ((float*)O1)[(size_t)rg * NNc + cg] = v;
                        O2[(size_t)rg * NNc + cg] = v * scale[rg];
                    }
                }
            }
        }
    }
}

// ---------------- graph preprocessing ----------------
__global__ void degrees_kernel(const int* __restrict__ src, const int* __restrict__ dst,
                               int* __restrict__ dout, int* __restrict__ din){
    int e = blockIdx.x * blockDim.x + threadIdx.x;
    if (e < NE_EDGES){
        atomicAdd(&dout[src[e]], 1);
        atomicAdd(&din[dst[e]], 1);
    }
}

__global__ void norm_kernel(const int* __restrict__ dout, const int* __restrict__ din,
                            float* __restrict__ ns, float* __restrict__ nd, int n){
    int i = blockIdx.x * blockDim.x + threadIdx.x;
    if (i < n){
        ns[i] = rsqrtf((float)(dout[i] > 1 ? dout[i] : 1));
        nd[i] = rsqrtf((float)(din[i]  > 1 ? din[i]  : 1));
    }
}

__global__ __launch_bounds__(256) void scan1_kernel(const int* __restrict__ din,
                                                    int* __restrict__ part,
                                                    int* __restrict__ bsum, int n){
    __shared__ int s[256];
    int i = blockIdx.x * 256 + threadIdx.x;
    int v = (i < n) ? din[i] : 0;
    s[threadIdx.x] = v;
    __syncthreads();
    for (int off = 1; off < 256; off <<= 1){
        int t = (threadIdx.x >= off) ? s[threadIdx.x - off] : 0;
        __syncthreads();
        s[threadIdx.x] += t;
        __syncthreads();
    }
    if (i < n) part[i] = s[threadIdx.x];
    if (threadIdx.x == 255) bsum[blockIdx.x] = s[255];
}

__global__ __launch_bounds__(512) void scan2_kernel(int* __restrict__ bsum, int nb){
    __shared__ int s[512];
    int v = (threadIdx.x < nb) ? bsum[threadIdx.x] : 0;
    s[threadIdx.x] = v;
    __syncthreads();
    for (int off = 1; off < 512; off <<= 1){
        int t = (threadIdx.x >= off) ? s[threadIdx.x - off] : 0;
        __syncthreads();
        s[threadIdx.x] += t;
        __syncthreads();
    }
    if (threadIdx.x < nb) bsum[threadIdx.x] = s[threadIdx.x];
}

__global__ void scan3_kernel(const int* __restrict__ part, const int* __restrict__ din,
                             const int* __restrict__ bsum, int* __restrict__ offs,
                             int* __restrict__ cur, int n){
    int i = blockIdx.x * 256 + threadIdx.x;
    if (i < n){
        int base = (blockIdx.x > 0) ? bsum[blockIdx.x - 1] : 0;
        int excl = base + part[i] - din[i];
        offs[i] = excl;
        cur[i]  = excl;
    }
}

__global__ void fill_kernel(const int* __restrict__ src, const int* __restrict__ dst,
                            int* __restrict__ cur, int* __restrict__ csr){
    int e = blockIdx.x * blockDim.x + threadIdx.x;
    if (e < NE_EDGES){
        int d = dst[e];
        int pos = atomicAdd(&cur[d], 1);
        csr[pos] = src[e];
    }
}

// ---------------- APPNP propagation ----------------
// hs = h * norm_src. One wave per node; 4 groups of 16 lanes walk edges
// concurrently, float4/lane row reads, cross-group shfl reduce.
// Writes houts = out*ns (iters 0..8) and/or hout = out (final iter).
__global__ __launch_bounds__(256) void propagate_kernel(
    const float* __restrict__ hs, const float* __restrict__ h0,
    float* __restrict__ hout, float* __restrict__ houts,
    const int* __restrict__ offs, const int* __restrict__ din,
    const int* __restrict__ csr,
    const float* __restrict__ ns, const float* __restrict__ nd)
{
    int wv   = threadIdx.x >> 6;
    int lane = threadIdx.x & 63;
    int grp  = lane >> 4;
    int gl   = lane & 15;
    int node = blockIdx.x * 4 + wv;
    if (node >= NN_NODES) return;
    int start = offs[node];
    int deg   = din[node];
    f32x4 acc = {};
    for (int j = grp; j < deg; j += 4){
        int s = csr[start + j];
        const f32x4 v = *(const f32x4*)(hs + (size_t)s * D_C + gl * 4);
        acc[0] += v[0]; acc[1] += v[1]; acc[2] += v[2]; acc[3] += v[3];
    }
    #pragma unroll
    for (int i = 0; i < 4; i++){
        acc[i] += __shfl_xor(acc[i], 16, 64);
        acc[i] += __shfl_xor(acc[i], 32, 64);
    }
    if (grp == 0){
        float ndv = nd[node];
        f32x4 h0v = *(const f32x4*)(h0 + (size_t)node * D_C + gl * 4);
        f32x4 out;
        #pragma unroll
        for (int i = 0; i < 4; i++) out[i] = 0.9f * acc[i] * ndv + 0.1f * h0v[i];
        if (hout)
            *(f32x4*)(hout + (size_t)node * D_C + gl * 4) = out;
        if (houts){
            float nsv = ns[node];
            f32x4 o2;
            #pragma unroll
            for (int i = 0; i < 4; i++) o2[i] = out[i] * nsv;
            *(f32x4*)(houts + (size_t)node * D_C + gl * 4) = o2;
        }
    }
}

// ---------------- launch ----------------
extern "C" void kernel_launch(void* const* d_in, const int* in_sizes, int n_in,
                              void* d_out, int out_size, void* d_ws, size_t ws_size,
                              hipStream_t stream)
{
    const float* features = (const float*)d_in[0];
    const int*   edge     = (const int*)d_in[1];
    const float* W0 = (const float*)d_in[2];
    const float* b0 = (const float*)d_in[3];
    const float* W1 = (const float*)d_in[4];
    const float* b1 = (const float*)d_in[5];
    const float* W2 = (const float*)d_in[6];
    const float* b2 = (const float*)d_in[7];
    const int* src = edge;
    const int* dst = edge + NE_EDGES;

    char* p = (char*)d_ws;
    auto alloc = [&](size_t bytes) -> char* {
        char* r = p;
        p += (bytes + 255) & ~(size_t)255;
        return r;
    };

    const size_t FEAT = (size_t)NN_NODES * D_IN * 2;   // 102.4 MB (bf16)
    const size_t HBUF = (size_t)NN_NODES * D_C * 4;    // 25.6 MB (fp32)

    unsigned short* w0hi = (unsigned short*)alloc((size_t)D_H0 * D_IN * 2);
    unsigned short* w0lo = (unsigned short*)alloc((size_t)D_H0 * D_IN * 2);
    unsigned short* w1hi = (unsigned short*)alloc((size_t)D_H1 * D_H0 * 2);
    unsigned short* w1lo = (unsigned short*)alloc((size_t)D_H1 * D_H0 * 2);
    unsigned short* w2hi = (unsigned short*)alloc((size_t)D_C * D_H1 * 2);
    unsigned short* w2lo = (unsigned short*)alloc((size_t)D_C * D_H1 * 2);
    char* R = alloc(2 * FEAT);                          // feature hi/lo region
    unsigned short* act1 = (unsigned short*)alloc(FEAT);
    int*   deg_out = (int*)alloc((size_t)NN_NODES * 4);
    int*   deg_in  = (int*)alloc((size_t)NN_NODES * 4);
    float* nsrc    = (float*)alloc((size_t)NN_NODES * 4);
    float* ndst    = (float*)alloc((size_t)NN_NODES * 4);
    int*   part    = (int*)alloc((size_t)NN_NODES * 4);
    int*   bsum    = (int*)alloc(2048);
    int*   offs    = (int*)alloc((size_t)NN_NODES * 4);
    int*   cur     = (int*)alloc((size_t)NN_NODES * 4);
    int*   csr     = (int*)alloc((size_t)NE_EDGES * 4);
    if ((size_t)(p - (char*)d_ws) > ws_size) return;

    // region R: features hi/lo during GEMM1; later reused (fhi/flo dead after GEMM1)
    unsigned short* fhi = (unsigned short*)R;
    unsigned short* flo = (unsigned short*)(R + FEAT);
    unsigned short* act2 = (unsigned short*)R;                       // 51.2 MB
    float* h0  = (float*)(R + (size_t)NN_NODES * D_H1 * 2);          // +51.2 MB
    float* h0s = (float*)((char*)h0 + HBUF);
    float* hAs = (float*)((char*)h0 + 2 * HBUF);
    float* hBs = (float*)((char*)h0 + 3 * HBUF);

    // --- graph preprocessing ---
    hipMemsetAsync(deg_out, 0, (size_t)NN_NODES * 4, stream);
    hipMemsetAsync(deg_in,  0, (size_t)NN_NODES * 4, stream);
    degrees_kernel<<<(NE_EDGES + 255) / 256, 256, 0, stream>>>(src, dst, deg_out, deg_in);
    norm_kernel<<<(NN_NODES + 255) / 256, 256, 0, stream>>>(deg_out, deg_in, nsrc, ndst, NN_NODES);
    int nb = (NN_NODES + 255) / 256;
    scan1_kernel<<<nb, 256, 0, stream>>>(deg_in, part, bsum, NN_NODES);
    scan2_kernel<<<1, 512, 0, stream>>>(bsum, nb);
    scan3_kernel<<<nb, 256, 0, stream>>>(part, deg_in, bsum, offs, cur, NN_NODES);
    fill_kernel<<<(NE_EDGES + 255) / 256, 256, 0, stream>>>(src, dst, cur, csr);

    // --- splits (features + weights) ---
    split8_kernel<<<(NN_NODES * D_IN / 8 + 255) / 256, 256, 0, stream>>>(
        features, fhi, flo, NN_NODES * D_IN / 8);
    split8_kernel<<<(D_H0 * D_IN / 8 + 255) / 256, 256, 0, stream>>>(W0, w0hi, w0lo, D_H0 * D_IN / 8);
    split8_kernel<<<(D_H1 * D_H0 / 8 + 255) / 256, 256, 0, stream>>>(W1, w1hi, w1lo, D_H1 * D_H0 / 8);
    split8_kernel<<<(D_C * D_H1 / 8 + 255) / 256, 256, 0, stream>>>(W2, w2hi, w2lo, D_C * D_H1 / 8);

    // --- MLP ---
    const int mtiles = (NN_NODES + 127) / 128;   // 782
    {   // L0: [100k,512]x[512,512]^T, split A, relu, bf16 out
        int nwg = mtiles * 4;
        gemm_kernel<true, true, 1, 128, 4><<<nwg, 256, 0, stream>>>(
            fhi, flo, w0hi, w0lo, b0, act1, nullptr, nullptr,
            NN_NODES, D_H0, D_IN, nwg / 8, nwg % 8);
    }
    {   // L1: [100k,512]x[256,512]^T, exact bf16 A, relu, bf16 out
        int nwg = mtiles * 2;
        gemm_kernel<false, true, 1, 128, 2><<<nwg, 256, 0, stream>>>(
            act1, nullptr, w1hi, w1lo, b1, act2, nullptr, nullptr,
            NN_NODES, D_H1, D_H0, nwg / 8, nwg % 8);
    }
    {   // L2: [100k,256]x[64,256]^T, dual fp32 out (h0, h0*ns)
        int nwg = mtiles;
        gemm_kernel<false, false, 2, 64, 1><<<nwg, 256, 0, stream>>>(
            act2, nullptr, w2hi, w2lo, b2, h0, h0s, nsrc,
            NN_NODES, D_C, D_H1, nwg / 8, nwg % 8);
    }

    // --- APPNP: 10 propagation steps ---
    const float* curs = h0s;
    float* bufss[2] = { hAs, hBs };
    int pb = (NN_NODES + 3) / 4;
    for (int it = 0; it < 10; it++){
        float* out  = (it == 9) ? (float*)d_out : nullptr;
        float* outs = (it == 9) ? nullptr       : bufss[it & 1];
        propagate_kernel<<<pb, 256, 0, stream>>>(curs, h0, out, outs, offs, deg_in, csr, nsrc, ndst);
        curs = outs;
    }
}

// Round 4
// 913.058 us; speedup vs baseline: 1.7841x; 1.1847x over previous
//
#include <hip/hip_runtime.h>
#include <hip/hip_bf16.h>

#define NN_NODES 100000
#define NE_EDGES 1000000
#define D_IN 512
#define D_H0 512
#define D_H1 256
#define D_C  64

using short8 = __attribute__((ext_vector_type(8))) short;
using f32x4  = __attribute__((ext_vector_type(4))) float;
using h16x8  = __attribute__((ext_vector_type(8))) _Float16;

static __device__ __forceinline__ unsigned short f2bf(float x){
    return __builtin_bit_cast(unsigned short, __float2bfloat16(x));
}
static __device__ __forceinline__ float bf2f(unsigned short u){
    return __bfloat162float(__builtin_bit_cast(__hip_bfloat16, u));
}

// async global->LDS, 16B/lane; LDS dest = wave-uniform base + lane*16
static __device__ __forceinline__ void gll16(const unsigned short* g, unsigned short* l){
    __builtin_amdgcn_global_load_lds(
        (const __attribute__((address_space(1))) unsigned int*)g,
        (__attribute__((address_space(3))) unsigned int*)l, 16, 0, 0);
}

// ---------------- fp32 -> bf16 (single), 8 elems/thread ----------------
__global__ __launch_bounds__(256) void tobf8_kernel(
    const float* __restrict__ w, unsigned short* __restrict__ o, int n8)
{
    int i = blockIdx.x * 256 + threadIdx.x;
    if (i >= n8) return;
    const f32x4 a = *(const f32x4*)(w + (size_t)i * 8);
    const f32x4 b = *(const f32x4*)(w + (size_t)i * 8 + 4);
    short8 h;
    #pragma unroll
    for (int j = 0; j < 4; j++){
        h[j]   = (short)f2bf(a[j]);
        h[j+4] = (short)f2bf(b[j]);
    }
    *(short8*)(o + (size_t)i * 8) = h;
}

// ---------------- fp32 -> bf16 hi + lo split (weights), 8 elems/thread ----------------
__global__ __launch_bounds__(256) void split8_kernel(
    const float* __restrict__ w, unsigned short* __restrict__ hi,
    unsigned short* __restrict__ lo, int n8)
{
    int i = blockIdx.x * 256 + threadIdx.x;
    if (i >= n8) return;
    const f32x4 a = *(const f32x4*)(w + (size_t)i * 8);
    const f32x4 b = *(const f32x4*)(w + (size_t)i * 8 + 4);
    short8 h, l;
    #pragma unroll
    for (int j = 0; j < 4; j++){
        unsigned short h1 = f2bf(a[j]);
        h[j] = (short)h1;  l[j] = (short)f2bf(a[j] - bf2f(h1));
        unsigned short h2 = f2bf(b[j]);
        h[j+4] = (short)h2; l[j+4] = (short)f2bf(b[j] - bf2f(h2));
    }
    *(short8*)(hi + (size_t)i * 8) = h;
    *(short8*)(lo + (size_t)i * 8) = l;
}

// ---------------- GEMM: C[M,NNc] = act( A[M,K] * B[NNc,K]^T + bias ) ----------------
// A single bf16; B split hi/lo bf16 -> 2 MFMA per fragment pair.
// Double-buffered LDS, 2-phase prefetch: STAGE(next) issued before compute(cur),
// one vmcnt-draining __syncthreads per k-step.
// LDS XOR-swizzle (both-sides): gll dest linear, global chunk pre-permuted by
// lane ((l&3)^((l>>3)&3)); reads use chunk fc^((r>>1)&3) -> conflict-free b128.
// OMODE: 1 bf16 out; 2 dual out (O1=v fp32, O2=(v*scale[row]) fp16).
template<bool RELU, int OMODE, int BN_T, int NBN>
__global__ __launch_bounds__(256) void gemm_kernel(
    const unsigned short* __restrict__ A,
    const unsigned short* __restrict__ Bhi,
    const unsigned short* __restrict__ Blo,
    const float* __restrict__ bias,
    void* __restrict__ O1, _Float16* __restrict__ O2, const float* __restrict__ scale,
    int M, int NNc, int K, int xq, int xr)
{
    constexpr int BM = 128, BK = 32;
    constexpr int NF   = BN_T / 32;        // n-fragments per wave
    constexpr int BBLK = BN_T / 16;        // 16-row gll blocks per B tile
    constexpr int TOT  = 8 + 2 * BBLK;     // gll ops per k-step (A + Bhi + Blo)
    constexpr int TPW  = TOT / 4;

    __shared__ unsigned short sA [2][BM * BK];
    __shared__ unsigned short sBh[2][BN_T * BK];
    __shared__ unsigned short sBl[2][BN_T * BK];

    const int tid  = threadIdx.x;
    const int lane = tid & 63;
    const int wv   = tid >> 6;
    const int wm   = wv >> 1;
    const int wn   = wv & 1;

    // bijective XCD-chunk swizzle (m204)
    const int bid = blockIdx.x;
    const int xcd = bid & 7;
    const int i8  = bid >> 3;
    const int L   = ((xcd < xr) ? xcd * (xq + 1) : xr * (xq + 1) + (xcd - xr) * xq) + i8;
    const int mt  = L / NBN;
    const int bn  = L - mt * NBN;
    const int bm0 = mt * BM;
    const int bn0 = bn * BN_T;

    const int lrow = lane >> 2;                               // row within 16-row block
    const int gch  = ((lane & 3) ^ ((lane >> 3) & 3)) * 8;    // swizzled global chunk (shorts)

    f32x4 acc[4][NF] = {};

    auto stage = [&](int b, int k0){
        #pragma unroll
        for (int t = 0; t < TPW; t++){
            int idx = t * 4 + wv;
            const unsigned short* g; unsigned short* lb; int rb; int base; int cl;
            if (idx < 8)           { g = A;   lb = sA[b];  rb = idx;            base = bm0; cl = 1; }
            else if (idx < 8+BBLK) { g = Bhi; lb = sBh[b]; rb = idx - 8;        base = bn0; cl = 0; }
            else                   { g = Blo; lb = sBl[b]; rb = idx - 8 - BBLK; base = bn0; cl = 0; }
            int row = base + rb * 16 + lrow;
            if (cl && row > M - 1) row = M - 1;
            gll16(g + (size_t)row * K + k0 + gch, lb + rb * 512);
        }
    };

    auto compute = [&](int b){
        const int fr = lane & 15;
        const int fc = lane >> 4;
        short8 bh[NF], bl[NF];
        #pragma unroll
        for (int nf = 0; nf < NF; nf++){
            int r = wn * (BN_T / 2) + nf * 16 + fr;
            int c = (fc ^ ((r >> 1) & 3)) * 8;
            bh[nf] = *(const short8*)&sBh[b][r * 32 + c];
            bl[nf] = *(const short8*)&sBl[b][r * 32 + c];
        }
        #pragma unroll
        for (int mf = 0; mf < 4; mf++){
            int r = wm * 64 + mf * 16 + fr;
            int c = (fc ^ ((r >> 1) & 3)) * 8;
            short8 a = *(const short8*)&sA[b][r * 32 + c];
            #pragma unroll
            for (int nf = 0; nf < NF; nf++){
                acc[mf][nf] = __builtin_amdgcn_mfma_f32_16x16x32_bf16(a, bh[nf], acc[mf][nf], 0, 0, 0);
                acc[mf][nf] = __builtin_amdgcn_mfma_f32_16x16x32_bf16(a, bl[nf], acc[mf][nf], 0, 0, 0);
            }
        }
    };

    const int NT = K / BK;
    stage(0, 0);
    __syncthreads();                  // drains vmcnt(0) before barrier
    int cur = 0;
    for (int t = 0; t < NT; t++){
        if (t + 1 < NT) stage(cur ^ 1, (t + 1) * BK);
        compute(cur);
        __syncthreads();              // drains own gll + syncs buffers
        cur ^= 1;
    }

    // ---- epilogue ----
    #pragma unroll
    for (int mf = 0; mf < 4; mf++){
        #pragma unroll
        for (int nf = 0; nf < NF; nf++){
            #pragma unroll
            for (int r = 0; r < 4; r++){
                int rg = bm0 + wm * 64 + mf * 16 + (lane >> 4) * 4 + r;
                int cg = bn0 + wn * (BN_T / 2) + nf * 16 + (lane & 15);
                if (rg < M){
                    float v = acc[mf][nf][r] + bias[cg];
                    if constexpr (RELU) v = fmaxf(v, 0.f);
                    if constexpr (OMODE == 1)
                        ((unsigned short*)O1)[(size_t)rg * NNc + cg] = f2bf(v);
                    else {
                        ((float*)O1)[(size_t)rg * NNc + cg] = v;
                        O2[(size_t)rg * NNc + cg] = (_Float16)(v * scale[rg]);
                    }
                }
            }
        }
    }
}

// ---------------- graph preprocessing ----------------
__global__ void degrees_kernel(const int* __restrict__ src, const int* __restrict__ dst,
                               int* __restrict__ dout, int* __restrict__ din){
    int e = blockIdx.x * blockDim.x + threadIdx.x;
    if (e < NE_EDGES){
        atomicAdd(&dout[src[e]], 1);
        atomicAdd(&din[dst[e]], 1);
    }
}

__global__ void norm_kernel(const int* __restrict__ dout, const int* __restrict__ din,
                            float* __restrict__ ns, float* __restrict__ nd, int n){
    int i = blockIdx.x * blockDim.x + threadIdx.x;
    if (i < n){
        ns[i] = rsqrtf((float)(dout[i] > 1 ? dout[i] : 1));
        nd[i] = rsqrtf((float)(din[i]  > 1 ? din[i]  : 1));
    }
}

__global__ __launch_bounds__(256) void scan1_kernel(const int* __restrict__ din,
                                                    int* __restrict__ part,
                                                    int* __restrict__ bsum, int n){
    __shared__ int s[256];
    int i = blockIdx.x * 256 + threadIdx.x;
    int v = (i < n) ? din[i] : 0;
    s[threadIdx.x] = v;
    __syncthreads();
    for (int off = 1; off < 256; off <<= 1){
        int t = (threadIdx.x >= off) ? s[threadIdx.x - off] : 0;
        __syncthreads();
        s[threadIdx.x] += t;
        __syncthreads();
    }
    if (i < n) part[i] = s[threadIdx.x];
    if (threadIdx.x == 255) bsum[blockIdx.x] = s[255];
}

__global__ __launch_bounds__(512) void scan2_kernel(int* __restrict__ bsum, int nb){
    __shared__ int s[512];
    int v = (threadIdx.x < nb) ? bsum[threadIdx.x] : 0;
    s[threadIdx.x] = v;
    __syncthreads();
    for (int off = 1; off < 512; off <<= 1){
        int t = (threadIdx.x >= off) ? s[threadIdx.x - off] : 0;
        __syncthreads();
        s[threadIdx.x] += t;
        __syncthreads();
    }
    if (threadIdx.x < nb) bsum[threadIdx.x] = s[threadIdx.x];
}

__global__ void scan3_kernel(const int* __restrict__ part, const int* __restrict__ din,
                             const int* __restrict__ bsum, int* __restrict__ offs,
                             int* __restrict__ cur, int n){
    int i = blockIdx.x * 256 + threadIdx.x;
    if (i < n){
        int base = (blockIdx.x > 0) ? bsum[blockIdx.x - 1] : 0;
        int excl = base + part[i] - din[i];
        offs[i] = excl;
        cur[i]  = excl;
    }
}

__global__ void fill_kernel(const int* __restrict__ src, const int* __restrict__ dst,
                            int* __restrict__ cur, int* __restrict__ csr){
    int e = blockIdx.x * blockDim.x + threadIdx.x;
    if (e < NE_EDGES){
        int d = dst[e];
        int pos = atomicAdd(&cur[d], 1);
        csr[pos] = src[e];
    }
}

// ---------------- APPNP propagation (fp16 gather state) ----------------
// hs = h * norm_src (fp16). One wave per node; 8 groups of 8 lanes walk edges,
// 16B (8 halfs) per lane, fp32 accumulate, cross-group shfl reduce.
__global__ __launch_bounds__(256) void propagate_kernel(
    const _Float16* __restrict__ hs, const float* __restrict__ h0,
    float* __restrict__ hout, _Float16* __restrict__ houts,
    const int* __restrict__ offs, const int* __restrict__ din,
    const int* __restrict__ csr,
    const float* __restrict__ ns, const float* __restrict__ nd)
{
    int wv   = threadIdx.x >> 6;
    int lane = threadIdx.x & 63;
    int grp  = lane >> 3;     // 0..7
    int gl   = lane & 7;      // 0..7
    int node = blockIdx.x * 4 + wv;
    if (node >= NN_NODES) return;
    int start = offs[node];
    int deg   = din[node];
    float acc[8] = {};
    for (int j = grp; j < deg; j += 8){
        int s = csr[start + j];
        h16x8 v = *(const h16x8*)(hs + (size_t)s * D_C + gl * 8);
        #pragma unroll
        for (int i = 0; i < 8; i++) acc[i] += (float)v[i];
    }
    #pragma unroll
    for (int i = 0; i < 8; i++){
        acc[i] += __shfl_xor(acc[i], 8, 64);
        acc[i] += __shfl_xor(acc[i], 16, 64);
        acc[i] += __shfl_xor(acc[i], 32, 64);
    }
    if (grp == 0){
        float ndv = nd[node];
        f32x4 h0a = *(const f32x4*)(h0 + (size_t)node * D_C + gl * 8);
        f32x4 h0b = *(const f32x4*)(h0 + (size_t)node * D_C + gl * 8 + 4);
        float out[8];
        #pragma unroll
        for (int i = 0; i < 4; i++){
            out[i]     = 0.9f * acc[i]     * ndv + 0.1f * h0a[i];
            out[i + 4] = 0.9f * acc[i + 4] * ndv + 0.1f * h0b[i];
        }
        if (hout){
            f32x4 oa, ob;
            #pragma unroll
            for (int i = 0; i < 4; i++){ oa[i] = out[i]; ob[i] = out[i + 4]; }
            *(f32x4*)(hout + (size_t)node * D_C + gl * 8)     = oa;
            *(f32x4*)(hout + (size_t)node * D_C + gl * 8 + 4) = ob;
        }
        if (houts){
            float nsv = ns[node];
            h16x8 o;
            #pragma unroll
            for (int i = 0; i < 8; i++) o[i] = (_Float16)(out[i] * nsv);
            *(h16x8*)(houts + (size_t)node * D_C + gl * 8) = o;
        }
    }
}

// ---------------- launch ----------------
extern "C" void kernel_launch(void* const* d_in, const int* in_sizes, int n_in,
                              void* d_out, int out_size, void* d_ws, size_t ws_size,
                              hipStream_t stream)
{
    const float* features = (const float*)d_in[0];
    const int*   edge     = (const int*)d_in[1];
    const float* W0 = (const float*)d_in[2];
    const float* b0 = (const float*)d_in[3];
    const float* W1 = (const float*)d_in[4];
    const float* b1 = (const float*)d_in[5];
    const float* W2 = (const float*)d_in[6];
    const float* b2 = (const float*)d_in[7];
    const int* src = edge;
    const int* dst = edge + NE_EDGES;

    char* p = (char*)d_ws;
    auto alloc = [&](size_t bytes) -> char* {
        char* r = p;
        p += (bytes + 255) & ~(size_t)255;
        return r;
    };

    const size_t FEAT  = (size_t)NN_NODES * D_IN * 2;   // 102.4 MB bf16
    const size_t HBUF  = (size_t)NN_NODES * D_C * 4;    // 25.6 MB fp32
    const size_t HBUFH = (size_t)NN_NODES * D_C * 2;    // 12.8 MB fp16

    unsigned short* w0hi = (unsigned short*)alloc((size_t)D_H0 * D_IN * 2);
    unsigned short* w0lo = (unsigned short*)alloc((size_t)D_H0 * D_IN * 2);
    unsigned short* w1hi = (unsigned short*)alloc((size_t)D_H1 * D_H0 * 2);
    unsigned short* w1lo = (unsigned short*)alloc((size_t)D_H1 * D_H0 * 2);
    unsigned short* w2hi = (unsigned short*)alloc((size_t)D_C * D_H1 * 2);
    unsigned short* w2lo = (unsigned short*)alloc((size_t)D_C * D_H1 * 2);
    char* R1 = alloc(FEAT);            // fbf; later act2
    char* R2 = alloc(FEAT);            // act1; later h0 + h0s + hAs + hBs
    int*   deg_out = (int*)alloc((size_t)NN_NODES * 4);
    int*   deg_in  = (int*)alloc((size_t)NN_NODES * 4);
    float* nsrc    = (float*)alloc((size_t)NN_NODES * 4);
    float* ndst    = (float*)alloc((size_t)NN_NODES * 4);
    int*   part    = (int*)alloc((size_t)NN_NODES * 4);
    int*   bsum    = (int*)alloc(2048);
    int*   offs    = (int*)alloc((size_t)NN_NODES * 4);
    int*   cur     = (int*)alloc((size_t)NN_NODES * 4);
    int*   csr     = (int*)alloc((size_t)NE_EDGES * 4);
    if ((size_t)(p - (char*)d_ws) > ws_size) return;

    unsigned short* fbf  = (unsigned short*)R1;          // dead after GEMM1... (GEMM2)
    unsigned short* act2 = (unsigned short*)R1;          // written by GEMM2
    unsigned short* act1 = (unsigned short*)R2;          // dead after GEMM2
    float*    h0  = (float*)R2;                          // written by GEMM3
    _Float16* h0s = (_Float16*)(R2 + HBUF);
    _Float16* hAs = (_Float16*)(R2 + HBUF + HBUFH);
    _Float16* hBs = (_Float16*)(R2 + HBUF + 2 * HBUFH);

    // --- graph preprocessing ---
    hipMemsetAsync(deg_out, 0, (size_t)NN_NODES * 4, stream);
    hipMemsetAsync(deg_in,  0, (size_t)NN_NODES * 4, stream);
    degrees_kernel<<<(NE_EDGES + 255) / 256, 256, 0, stream>>>(src, dst, deg_out, deg_in);
    norm_kernel<<<(NN_NODES + 255) / 256, 256, 0, stream>>>(deg_out, deg_in, nsrc, ndst, NN_NODES);
    int nb = (NN_NODES + 255) / 256;
    scan1_kernel<<<nb, 256, 0, stream>>>(deg_in, part, bsum, NN_NODES);
    scan2_kernel<<<1, 512, 0, stream>>>(bsum, nb);
    scan3_kernel<<<nb, 256, 0, stream>>>(part, deg_in, bsum, offs, cur, NN_NODES);
    fill_kernel<<<(NE_EDGES + 255) / 256, 256, 0, stream>>>(src, dst, cur, csr);

    // --- conversions ---
    tobf8_kernel<<<(NN_NODES * D_IN / 8 + 255) / 256, 256, 0, stream>>>(
        features, fbf, NN_NODES * D_IN / 8);
    split8_kernel<<<(D_H0 * D_IN / 8 + 255) / 256, 256, 0, stream>>>(W0, w0hi, w0lo, D_H0 * D_IN / 8);
    split8_kernel<<<(D_H1 * D_H0 / 8 + 255) / 256, 256, 0, stream>>>(W1, w1hi, w1lo, D_H1 * D_H0 / 8);
    split8_kernel<<<(D_C * D_H1 / 8 + 255) / 256, 256, 0, stream>>>(W2, w2hi, w2lo, D_C * D_H1 / 8);

    // --- MLP ---
    const int mtiles = (NN_NODES + 127) / 128;   // 782
    {   // L0: [100k,512] x [512,512]^T, relu, bf16 out
        int nwg = mtiles * 4;
        gemm_kernel<true, 1, 128, 4><<<nwg, 256, 0, stream>>>(
            fbf, w0hi, w0lo, b0, act1, nullptr, nullptr,
            NN_NODES, D_H0, D_IN, nwg / 8, nwg % 8);
    }
    {   // L1: [100k,512] x [256,512]^T, relu, bf16 out
        int nwg = mtiles * 2;
        gemm_kernel<true, 1, 128, 2><<<nwg, 256, 0, stream>>>(
            act1, w1hi, w1lo, b1, act2, nullptr, nullptr,
            NN_NODES, D_H1, D_H0, nwg / 8, nwg % 8);
    }
    {   // L2: [100k,256] x [64,256]^T, dual out (h0 fp32, h0s=h0*ns fp16)
        int nwg = mtiles;
        gemm_kernel<false, 2, 64, 1><<<nwg, 256, 0, stream>>>(
            act2, w2hi, w2lo, b2, h0, h0s, nsrc,
            NN_NODES, D_C, D_H1, nwg / 8, nwg % 8);
    }

    // --- APPNP: 10 propagation steps ---
    const _Float16* curs = h0s;
    _Float16* bufss[2] = { hAs, hBs };
    int pb = (NN_NODES + 3) / 4;
    for (int it = 0; it < 10; it++){
        float*    out  = (it == 9) ? (float*)d_out : nullptr;
        _Float16* outs = (it == 9) ? nullptr       : bufss[it & 1];
        propagate_kernel<<<pb, 256, 0, stream>>>(curs, h0, out, outs, offs, deg_in, csr, nsrc, ndst);
        curs = outs;
    }
}

// Round 5
// 875.686 us; speedup vs baseline: 1.8602x; 1.0427x over previous
//
#include <hip/hip_runtime.h>
#include <hip/hip_bf16.h>

#define NN_NODES 100000
#define NE_EDGES 1000000
#define D_IN 512
#define D_H0 512
#define D_H1 256
#define D_C  64

using f32x4  = __attribute__((ext_vector_type(4))) float;
using h16x8  = __attribute__((ext_vector_type(8))) _Float16;
using s16x8  = __attribute__((ext_vector_type(8))) short;

// async global->LDS, 16B/lane; LDS dest = wave-uniform base + lane*16
static __device__ __forceinline__ void gll16(const _Float16* g, _Float16* l){
    __builtin_amdgcn_global_load_lds(
        (const __attribute__((address_space(1))) unsigned int*)g,
        (__attribute__((address_space(3))) unsigned int*)l, 16, 0, 0);
}

// ---------------- fp32 -> fp16, 8 elems/thread ----------------
__global__ __launch_bounds__(256) void tof16_kernel(
    const float* __restrict__ w, _Float16* __restrict__ o, int n8)
{
    int i = blockIdx.x * 256 + threadIdx.x;
    if (i >= n8) return;
    const f32x4 a = *(const f32x4*)(w + (size_t)i * 8);
    const f32x4 b = *(const f32x4*)(w + (size_t)i * 8 + 4);
    h16x8 h;
    #pragma unroll
    for (int j = 0; j < 4; j++){
        h[j]   = (_Float16)a[j];
        h[j+4] = (_Float16)b[j];
    }
    *(h16x8*)(o + (size_t)i * 8) = h;
}

// ---------------- GEMM: C[M,NNc] = act( A[M,K] * B[NNc,K]^T + bias ) ----------------
// A, B fp16; fp32 accumulate via mfma_f32_16x16x32_f16 (1 MFMA per fragment pair).
// Double-buffered LDS, prefetch next k-tile before compute, one barrier/k-step.
// LDS XOR-swizzle both-sides: gll dest linear, global chunk pre-permuted
// ((l&3)^((l>>3)&3)); reads use chunk fc^((r>>1)&3) -> conflict-free ds_read_b128.
// OMODE: 1 fp16 out; 2 dual out (O1=v fp32, O2=(v*scale[row]) fp16).
template<bool RELU, int OMODE, int BN_T, int NBN>
__global__ __launch_bounds__(256) void gemm_kernel(
    const _Float16* __restrict__ A,
    const _Float16* __restrict__ B,
    const float* __restrict__ bias,
    void* __restrict__ O1, _Float16* __restrict__ O2, const float* __restrict__ scale,
    int M, int NNc, int K, int xq, int xr)
{
    constexpr int BM = 128, BK = 32;
    constexpr int NF   = BN_T / 32;        // n-fragments per wave
    constexpr int BBLK = BN_T / 16;        // 16-row gll blocks per B tile
    constexpr int TOT  = 8 + BBLK;         // gll ops per k-step
    constexpr int TPW  = (TOT + 3) / 4;

    __shared__ _Float16 sA[2][BM * BK];
    __shared__ _Float16 sB[2][BN_T * BK];

    const int tid  = threadIdx.x;
    const int lane = tid & 63;
    const int wv   = tid >> 6;
    const int wm   = wv >> 1;
    const int wn   = wv & 1;

    // bijective XCD-chunk swizzle (m204)
    const int bid = blockIdx.x;
    const int xcd = bid & 7;
    const int i8  = bid >> 3;
    const int L   = ((xcd < xr) ? xcd * (xq + 1) : xr * (xq + 1) + (xcd - xr) * xq) + i8;
    const int mt  = L / NBN;
    const int bn  = L - mt * NBN;
    const int bm0 = mt * BM;
    const int bn0 = bn * BN_T;

    const int lrow = lane >> 2;                               // row within 16-row block
    const int gch  = ((lane & 3) ^ ((lane >> 3) & 3)) * 8;    // swizzled global chunk (halfs)

    f32x4 acc[4][NF] = {};

    auto stage = [&](int b, int k0){
        #pragma unroll
        for (int t = 0; t < TPW; t++){
            int idx = t * 4 + wv;
            if (idx >= TOT) break;
            const _Float16* g; _Float16* lb; int rb; int base; int cl;
            if (idx < 8) { g = A; lb = sA[b]; rb = idx;     base = bm0; cl = 1; }
            else         { g = B; lb = sB[b]; rb = idx - 8; base = bn0; cl = 0; }
            int row = base + rb * 16 + lrow;
            if (cl && row > M - 1) row = M - 1;
            gll16(g + (size_t)row * K + k0 + gch, lb + rb * 512);
        }
    };

    auto compute = [&](int b){
        const int fr = lane & 15;
        const int fc = lane >> 4;
        h16x8 bf[NF];
        #pragma unroll
        for (int nf = 0; nf < NF; nf++){
            int r = wn * (BN_T / 2) + nf * 16 + fr;
            int c = (fc ^ ((r >> 1) & 3)) * 8;
            bf[nf] = *(const h16x8*)&sB[b][r * 32 + c];
        }
        #pragma unroll
        for (int mf = 0; mf < 4; mf++){
            int r = wm * 64 + mf * 16 + fr;
            int c = (fc ^ ((r >> 1) & 3)) * 8;
            h16x8 a = *(const h16x8*)&sA[b][r * 32 + c];
            #pragma unroll
            for (int nf = 0; nf < NF; nf++)
                acc[mf][nf] = __builtin_amdgcn_mfma_f32_16x16x32_f16(a, bf[nf], acc[mf][nf], 0, 0, 0);
        }
    };

    const int NT = K / BK;
    stage(0, 0);
    __syncthreads();
    int cur = 0;
    for (int t = 0; t < NT; t++){
        if (t + 1 < NT) stage(cur ^ 1, (t + 1) * BK);
        compute(cur);
        __syncthreads();
        cur ^= 1;
    }

    // ---- epilogue ----
    #pragma unroll
    for (int mf = 0; mf < 4; mf++){
        #pragma unroll
        for (int nf = 0; nf < NF; nf++){
            #pragma unroll
            for (int r = 0; r < 4; r++){
                int rg = bm0 + wm * 64 + mf * 16 + (lane >> 4) * 4 + r;
                int cg = bn0 + wn * (BN_T / 2) + nf * 16 + (lane & 15);
                if (rg < M){
                    float v = acc[mf][nf][r] + bias[cg];
                    if constexpr (RELU) v = fmaxf(v, 0.f);
                    if constexpr (OMODE == 1)
                        ((_Float16*)O1)[(size_t)rg * NNc + cg] = (_Float16)v;
                    else {
                        ((float*)O1)[(size_t)rg * NNc + cg] = v;
                        O2[(size_t)rg * NNc + cg] = (_Float16)(v * scale[rg]);
                    }
                }
            }
        }
    }
}

// ---------------- graph preprocessing ----------------
__global__ void degrees_kernel(const int* __restrict__ src, const int* __restrict__ dst,
                               int* __restrict__ dout, int* __restrict__ din){
    int e = blockIdx.x * blockDim.x + threadIdx.x;
    if (e < NE_EDGES){
        atomicAdd(&dout[src[e]], 1);
        atomicAdd(&din[dst[e]], 1);
    }
}

__global__ void norm_kernel(const int* __restrict__ dout, const int* __restrict__ din,
                            float* __restrict__ ns, float* __restrict__ nd, int n){
    int i = blockIdx.x * blockDim.x + threadIdx.x;
    if (i < n){
        ns[i] = rsqrtf((float)(dout[i] > 1 ? dout[i] : 1));
        nd[i] = rsqrtf((float)(din[i]  > 1 ? din[i]  : 1));
    }
}

__global__ __launch_bounds__(256) void scan1_kernel(const int* __restrict__ din,
                                                    int* __restrict__ part,
                                                    int* __restrict__ bsum, int n){
    __shared__ int s[256];
    int i = blockIdx.x * 256 + threadIdx.x;
    int v = (i < n) ? din[i] : 0;
    s[threadIdx.x] = v;
    __syncthreads();
    for (int off = 1; off < 256; off <<= 1){
        int t = (threadIdx.x >= off) ? s[threadIdx.x - off] : 0;
        __syncthreads();
        s[threadIdx.x] += t;
        __syncthreads();
    }
    if (i < n) part[i] = s[threadIdx.x];
    if (threadIdx.x == 255) bsum[blockIdx.x] = s[255];
}

__global__ __launch_bounds__(512) void scan2_kernel(int* __restrict__ bsum, int nb){
    __shared__ int s[512];
    int v = (threadIdx.x < nb) ? bsum[threadIdx.x] : 0;
    s[threadIdx.x] = v;
    __syncthreads();
    for (int off = 1; off < 512; off <<= 1){
        int t = (threadIdx.x >= off) ? s[threadIdx.x - off] : 0;
        __syncthreads();
        s[threadIdx.x] += t;
        __syncthreads();
    }
    if (threadIdx.x < nb) bsum[threadIdx.x] = s[threadIdx.x];
}

__global__ void scan3_kernel(const int* __restrict__ part, const int* __restrict__ din,
                             const int* __restrict__ bsum, int* __restrict__ offs,
                             int* __restrict__ cur, int n){
    int i = blockIdx.x * 256 + threadIdx.x;
    if (i < n){
        int base = (blockIdx.x > 0) ? bsum[blockIdx.x - 1] : 0;
        int excl = base + part[i] - din[i];
        offs[i] = excl;
        cur[i]  = excl;
    }
}

__global__ void fill_kernel(const int* __restrict__ src, const int* __restrict__ dst,
                            int* __restrict__ cur, int* __restrict__ csr){
    int e = blockIdx.x * blockDim.x + threadIdx.x;
    if (e < NE_EDGES){
        int d = dst[e];
        int pos = atomicAdd(&cur[d], 1);
        csr[pos] = src[e];
    }
}

// ---------------- APPNP propagation (fp16 gather state) ----------------
// hs = h * norm_src (fp16). One wave per node; 8 groups of 8 lanes walk edges,
// 16B (8 halfs) per lane, fp32 accumulate, cross-group shfl reduce.
__global__ __launch_bounds__(256) void propagate_kernel(
    const _Float16* __restrict__ hs, const float* __restrict__ h0,
    float* __restrict__ hout, _Float16* __restrict__ houts,
    const int* __restrict__ offs, const int* __restrict__ din,
    const int* __restrict__ csr,
    const float* __restrict__ ns, const float* __restrict__ nd)
{
    int wv   = threadIdx.x >> 6;
    int lane = threadIdx.x & 63;
    int grp  = lane >> 3;     // 0..7
    int gl   = lane & 7;      // 0..7
    int node = blockIdx.x * 4 + wv;
    if (node >= NN_NODES) return;
    int start = offs[node];
    int deg   = din[node];
    float acc[8] = {};
    for (int j = grp; j < deg; j += 8){
        int s = csr[start + j];
        h16x8 v = *(const h16x8*)(hs + (size_t)s * D_C + gl * 8);
        #pragma unroll
        for (int i = 0; i < 8; i++) acc[i] += (float)v[i];
    }
    #pragma unroll
    for (int i = 0; i < 8; i++){
        acc[i] += __shfl_xor(acc[i], 8, 64);
        acc[i] += __shfl_xor(acc[i], 16, 64);
        acc[i] += __shfl_xor(acc[i], 32, 64);
    }
    if (grp == 0){
        float ndv = nd[node];
        f32x4 h0a = *(const f32x4*)(h0 + (size_t)node * D_C + gl * 8);
        f32x4 h0b = *(const f32x4*)(h0 + (size_t)node * D_C + gl * 8 + 4);
        float out[8];
        #pragma unroll
        for (int i = 0; i < 4; i++){
            out[i]     = 0.9f * acc[i]     * ndv + 0.1f * h0a[i];
            out[i + 4] = 0.9f * acc[i + 4] * ndv + 0.1f * h0b[i];
        }
        if (hout){
            f32x4 oa, ob;
            #pragma unroll
            for (int i = 0; i < 4; i++){ oa[i] = out[i]; ob[i] = out[i + 4]; }
            *(f32x4*)(hout + (size_t)node * D_C + gl * 8)     = oa;
            *(f32x4*)(hout + (size_t)node * D_C + gl * 8 + 4) = ob;
        }
        if (houts){
            float nsv = ns[node];
            h16x8 o;
            #pragma unroll
            for (int i = 0; i < 8; i++) o[i] = (_Float16)(out[i] * nsv);
            *(h16x8*)(houts + (size_t)node * D_C + gl * 8) = o;
        }
    }
}

// ---------------- launch ----------------
extern "C" void kernel_launch(void* const* d_in, const int* in_sizes, int n_in,
                              void* d_out, int out_size, void* d_ws, size_t ws_size,
                              hipStream_t stream)
{
    const float* features = (const float*)d_in[0];
    const int*   edge     = (const int*)d_in[1];
    const float* W0 = (const float*)d_in[2];
    const float* b0 = (const float*)d_in[3];
    const float* W1 = (const float*)d_in[4];
    const float* b1 = (const float*)d_in[5];
    const float* W2 = (const float*)d_in[6];
    const float* b2 = (const float*)d_in[7];
    const int* src = edge;
    const int* dst = edge + NE_EDGES;

    char* p = (char*)d_ws;
    auto alloc = [&](size_t bytes) -> char* {
        char* r = p;
        p += (bytes + 255) & ~(size_t)255;
        return r;
    };

    const size_t FEAT  = (size_t)NN_NODES * D_IN * 2;   // 102.4 MB fp16
    const size_t HBUF  = (size_t)NN_NODES * D_C * 4;    // 25.6 MB fp32
    const size_t HBUFH = (size_t)NN_NODES * D_C * 2;    // 12.8 MB fp16

    _Float16* w0f = (_Float16*)alloc((size_t)D_H0 * D_IN * 2);
    _Float16* w1f = (_Float16*)alloc((size_t)D_H1 * D_H0 * 2);
    _Float16* w2f = (_Float16*)alloc((size_t)D_C * D_H1 * 2);
    char* R1 = alloc(FEAT);            // fhf; later act2
    char* R2 = alloc(FEAT);            // act1; later h0 + h0s + hAs + hBs
    int*   deg_out = (int*)alloc((size_t)NN_NODES * 4);
    int*   deg_in  = (int*)alloc((size_t)NN_NODES * 4);
    float* nsrc    = (float*)alloc((size_t)NN_NODES * 4);
    float* ndst    = (float*)alloc((size_t)NN_NODES * 4);
    int*   part    = (int*)alloc((size_t)NN_NODES * 4);
    int*   bsum    = (int*)alloc(2048);
    int*   offs    = (int*)alloc((size_t)NN_NODES * 4);
    int*   cur     = (int*)alloc((size_t)NN_NODES * 4);
    int*   csr     = (int*)alloc((size_t)NE_EDGES * 4);
    if ((size_t)(p - (char*)d_ws) > ws_size) return;

    _Float16* fhf  = (_Float16*)R1;          // dead after GEMM1
    _Float16* act2 = (_Float16*)R1;          // written by GEMM2
    _Float16* act1 = (_Float16*)R2;          // dead after GEMM2
    float*    h0  = (float*)R2;              // written by GEMM3
    _Float16* h0s = (_Float16*)(R2 + HBUF);
    _Float16* hAs = (_Float16*)(R2 + HBUF + HBUFH);
    _Float16* hBs = (_Float16*)(R2 + HBUF + 2 * HBUFH);

    // --- graph preprocessing ---
    hipMemsetAsync(deg_out, 0, (size_t)NN_NODES * 4, stream);
    hipMemsetAsync(deg_in,  0, (size_t)NN_NODES * 4, stream);
    degrees_kernel<<<(NE_EDGES + 255) / 256, 256, 0, stream>>>(src, dst, deg_out, deg_in);
    norm_kernel<<<(NN_NODES + 255) / 256, 256, 0, stream>>>(deg_out, deg_in, nsrc, ndst, NN_NODES);
    int nb = (NN_NODES + 255) / 256;
    scan1_kernel<<<nb, 256, 0, stream>>>(deg_in, part, bsum, NN_NODES);
    scan2_kernel<<<1, 512, 0, stream>>>(bsum, nb);
    scan3_kernel<<<nb, 256, 0, stream>>>(part, deg_in, bsum, offs, cur, NN_NODES);
    fill_kernel<<<(NE_EDGES + 255) / 256, 256, 0, stream>>>(src, dst, cur, csr);

    // --- conversions (fp32 -> fp16) ---
    tof16_kernel<<<(NN_NODES * D_IN / 8 + 255) / 256, 256, 0, stream>>>(
        features, fhf, NN_NODES * D_IN / 8);
    tof16_kernel<<<(D_H0 * D_IN / 8 + 255) / 256, 256, 0, stream>>>(W0, w0f, D_H0 * D_IN / 8);
    tof16_kernel<<<(D_H1 * D_H0 / 8 + 255) / 256, 256, 0, stream>>>(W1, w1f, D_H1 * D_H0 / 8);
    tof16_kernel<<<(D_C * D_H1 / 8 + 255) / 256, 256, 0, stream>>>(W2, w2f, D_C * D_H1 / 8);

    // --- MLP ---
    const int mtiles = (NN_NODES + 127) / 128;   // 782
    {   // L0: [100k,512] x [512,512]^T, relu, fp16 out
        int nwg = mtiles * 4;
        gemm_kernel<true, 1, 128, 4><<<nwg, 256, 0, stream>>>(
            fhf, w0f, b0, act1, nullptr, nullptr,
            NN_NODES, D_H0, D_IN, nwg / 8, nwg % 8);
    }
    {   // L1: [100k,512] x [256,512]^T, relu, fp16 out
        int nwg = mtiles * 2;
        gemm_kernel<true, 1, 128, 2><<<nwg, 256, 0, stream>>>(
            act1, w1f, b1, act2, nullptr, nullptr,
            NN_NODES, D_H1, D_H0, nwg / 8, nwg % 8);
    }
    {   // L2: [100k,256] x [64,256]^T, dual out (h0 fp32, h0s=h0*ns fp16)
        int nwg = mtiles;
        gemm_kernel<false, 2, 64, 1><<<nwg, 256, 0, stream>>>(
            act2, w2f, b2, h0, h0s, nsrc,
            NN_NODES, D_C, D_H1, nwg / 8, nwg % 8);
    }

    // --- APPNP: 10 propagation steps ---
    const _Float16* curs = h0s;
    _Float16* bufss[2] = { hAs, hBs };
    int pb = (NN_NODES + 3) / 4;
    for (int it = 0; it < 10; it++){
        float*    out  = (it == 9) ? (float*)d_out : nullptr;
        _Float16* outs = (it == 9) ? nullptr       : bufss[it & 1];
        propagate_kernel<<<pb, 256, 0, stream>>>(curs, h0, out, outs, offs, deg_in, csr, nsrc, ndst);
        curs = outs;
    }
}